// Round 3
// baseline (418.210 us; speedup 1.0000x reference)
//
#include <hip/hip_runtime.h>
#include <stdint.h>

typedef __attribute__((ext_vector_type(4))) int v4i;

#define BATCH 8192
#define KDIM  4096
#define NOUT  4096

// pack x: fp32 -> i8 {1,0}, 16 elems/thread, 16B stores
__global__ __launch_bounds__(256) void pack_x(const float* __restrict__ x,
                                              uint4* __restrict__ xb) {
    size_t t = (size_t)blockIdx.x * 256 + threadIdx.x;
    const float4* xp = (const float4*)x + t * 4;
    uint32_t o[4];
    #pragma unroll
    for (int i = 0; i < 4; ++i) {
        float4 f = xp[i];
        o[i] = (f.x > 0.f ? 1u : 0u)
             | ((f.y > 0.f ? 1u : 0u) << 8)
             | ((f.z > 0.f ? 1u : 0u) << 16)
             | ((f.w > 0.f ? 1u : 0u) << 24);
    }
    xb[t] = make_uint4(o[0], o[1], o[2], o[3]);
}

// pack W: fp32 -> i8 {+1,-1}, 16 elems/thread, 16B stores
__global__ __launch_bounds__(256) void pack_w(const float* __restrict__ w,
                                              uint4* __restrict__ wb) {
    size_t t = (size_t)blockIdx.x * 256 + threadIdx.x;
    const float4* wp = (const float4*)w + t * 4;
    uint32_t o[4];
    #pragma unroll
    for (int i = 0; i < 4; ++i) {
        float4 f = wp[i];
        o[i] = (f.x > 0.f ? 0x01u : 0xFFu)
             | ((f.y > 0.f ? 0x01u : 0xFFu) << 8)
             | ((f.z > 0.f ? 0x01u : 0xFFu) << 16)
             | ((f.w > 0.f ? 0x01u : 0xFFu) << 24);
    }
    wb[t] = make_uint4(o[0], o[1], o[2], o[3]);
}

__device__ __forceinline__ void glo16(const int8_t* g, int8_t* l) {
    __builtin_amdgcn_global_load_lds(
        (__attribute__((address_space(1))) const void*)g,
        (__attribute__((address_space(3))) void*)l, 16, 0, 0);
}

// C[M,N] = A[M,K] * B[N,K]^T, i8 in, f32 out (integer-exact).
// R3: double-buffered BK=64. Tile kt+1's global_load_lds are issued at the
// TOP of iteration kt (into buf 1-cur); ds_read+MFMA on buf cur runs while
// those loads are in flight; the single __syncthreads (whose vmcnt(0) drain
// is the known structural stall) now overlaps ~350-400 cyc of compute
// instead of immediately following the loads. One barrier per k-tile.
// Staging/swizzle identical to R1 (measured: 0 bank conflicts, absmax 0):
// 64B LDS rows, chunk c of row r stored at c^((r>>1)&3) via the GLOBAL
// fetch address (global_load_lds dst = wave base + lane*16).
__global__ __launch_bounds__(256) void bin_gemm(const int8_t* __restrict__ A,
                                                const int8_t* __restrict__ B,
                                                float* __restrict__ C) {
    __shared__ __align__(16) int8_t smA[2][128 * 64];
    __shared__ __align__(16) int8_t smB[2][128 * 64];

    const int tid  = threadIdx.x;
    const int w    = tid >> 6;          // wave 0..3
    const int lane = tid & 63;
    const int q    = lane >> 4;         // quad 0..3
    const int mp   = lane & 15;

    const int Mbase = blockIdx.y * 128;
    const int Nbase = blockIdx.x * 128;
    const int wm = (w >> 1) * 64;       // wave M offset in tile
    const int wn = (w & 1) * 64;        // wave N offset in tile

    // Staging: wave stages rows g0..g0+15 and g1..g1+15 of A and of B.
    // lane -> (row = lane>>2, global chunk = (lane&3)^((lane>>3)&3)).
    const int srow = lane >> 2;
    const int swz  = ((lane & 3) ^ ((lane >> 3) & 3)) * 16;
    const int g0   = (w * 2 + 0) * 16;
    const int g1   = (w * 2 + 1) * 16;

    const int8_t* Ab = A + (size_t)Mbase * KDIM;   // uniform bases
    const int8_t* Bb = B + (size_t)Nbase * KDIM;
    const int of0 = (g0 + srow) * KDIM + swz;       // small per-lane offsets
    const int of1 = (g1 + srow) * KDIM + swz;

    // Fragment read: quad q reads k-chunk q of row mp; physical slot
    // = (q ^ ((mp>>1)&3)) (R1-verified).
    const int slot = (q ^ ((mp >> 1) & 3)) * 16;

    v4i acc[4][4] = {};

    auto stage = [&](int kt, int buf) {
        const int ko = kt * 64;
        glo16(Ab + ko + of0, &smA[buf][g0 * 64]);
        glo16(Ab + ko + of1, &smA[buf][g1 * 64]);
        glo16(Bb + ko + of0, &smB[buf][g0 * 64]);
        glo16(Bb + ko + of1, &smB[buf][g1 * 64]);
    };

    auto compute = [&](int buf) {
        v4i af[4], bf[4];
        #pragma unroll
        for (int i = 0; i < 4; ++i)
            af[i] = *(const v4i*)(&smA[buf][(wm + i * 16 + mp) * 64 + slot]);
        #pragma unroll
        for (int i = 0; i < 4; ++i)
            bf[i] = *(const v4i*)(&smB[buf][(wn + i * 16 + mp) * 64 + slot]);
        #pragma unroll
        for (int mi = 0; mi < 4; ++mi)
            #pragma unroll
            for (int ni = 0; ni < 4; ++ni)
                acc[mi][ni] = __builtin_amdgcn_mfma_i32_16x16x64_i8(
                    af[mi], bf[ni], acc[mi][ni], 0, 0, 0);
    };

    stage(0, 0);
    __syncthreads();            // drain tile-0 loads

    for (int kt = 0; kt < KDIM / 64; kt += 2) {
        stage(kt + 1, 1);       // prefetch next tile into buf1 (in flight)
        compute(0);             // MFMA on buf0 overlaps the prefetch
        __syncthreads();        // vmcnt(0) drain, mostly already landed
        stage((kt + 2) & 63, 0);// (kt+2)&63: last iter harmlessly reloads 0
        compute(1);
        __syncthreads();
    }

    // C/D layout: col = lane&15, row = quad*4 + reg (shape-determined).
    float* Cp = C + (size_t)(Mbase + wm + q * 4) * NOUT + (Nbase + wn + mp);
    #pragma unroll
    for (int mi = 0; mi < 4; ++mi)
        #pragma unroll
        for (int ni = 0; ni < 4; ++ni)
            #pragma unroll
            for (int r = 0; r < 4; ++r)
                Cp[(size_t)(mi * 16 + r) * NOUT + ni * 16] = (float)acc[mi][ni][r];
}

extern "C" void kernel_launch(void* const* d_in, const int* in_sizes, int n_in,
                              void* d_out, int out_size, void* d_ws, size_t ws_size,
                              hipStream_t stream) {
    const float* x = (const float*)d_in[0];   // [8192, 4096] f32
    const float* W = (const float*)d_in[1];   // [4096, 4096] f32, values +/-1
    float* out = (float*)d_out;               // [8192, 4096] f32

    int8_t* xb = (int8_t*)d_ws;                           // 32 MiB
    int8_t* wb = (int8_t*)d_ws + (size_t)BATCH * KDIM;    // 16 MiB (48 MiB ws total)

    pack_x<<<(BATCH * (size_t)KDIM / 16) / 256, 256, 0, stream>>>(x, (uint4*)xb);
    pack_w<<<((size_t)NOUT * KDIM / 16) / 256, 256, 0, stream>>>(W, (uint4*)wb);

    dim3 grid(NOUT / 128, BATCH / 128);   // (32, 64) = 2048 blocks
    bin_gemm<<<grid, 256, 0, stream>>>(xb, wb, out);
}